// Round 2
// baseline (376.287 us; speedup 1.0000x reference)
//
#include <hip/hip_runtime.h>

// NaturalVariation: out = x + softmax(x@W_sel + b_sel)@patterns + EMA(0.05*noise)
// B=4, T=8192, H=1024, P=8. fp32 in/out. Ideal traffic ~447 MB -> ~71 us floor.
//
// EMA truncation: 0.9^64 = 1.18e-3 -> worst-case dropped tail
// <= 0.05*5sigma*0.9^65/(1-0.9)*0.1 ~ 3e-4 << 0.11 threshold. So chunks of
// T are independent given a 64-step warm-up -> no serial scan, no carries.
//
// R2 changes vs 356us:
//  - kB: CHUNK 128->64 => grid 1024->2048 blocks = 32 waves/CU (was 16).
//    R1 showed kernel is latency-bound (Occ 39%, VALUBusy 15%, HBM 39%);
//    occupancy was the lever (R0->R1: 10%->39% gave 1.75x). Warm-up rereads
//    are L2/LLC hits (R1: FETCH 165MB < 320MB compulsory+warm). Unroll 8.
//  - kA: 8 tokens/wave + exchange-halves butterfly (63 shfl+add for all
//    8 tokens, vs 6x16 per 2 tokens before), W_sel loads amortized 4x,
//    coalesced full-wave store of 64 weights.

#define T_LEN 8192
#define H_DIM 1024
#define B_DIM 4
#define NPAT 8
#define CHUNK 64             // tokens per kB block
#define WARM 64              // EMA warm-up steps
#define NCHUNK (T_LEN / CHUNK)   // 128 chunks per batch row
#define HSPLIT 4             // kB blocks per chunk (H slices)
#define HSL (H_DIM / HSPLIT) // 256 columns per block

static_assert(WARM <= CHUNK, "warm-up must stay within previous chunk");

// ---------------- Kernel A: per-token softmax weights --------------------
// 4 waves/block, 8 tokens per wave. Accumulate phase: lane l covers
// h = r*64 + l for r=0..15, keeping 64 partials a[j*8+p] (token j, pat p).
// Reduce phase: 6-step exchange-halves butterfly -> lane l holds the full
// logit for (token l>>3, pattern l&7). Softmax within 8-lane groups.
__global__ __launch_bounds__(256) void kA_weights(
    const float* __restrict__ x, const float* __restrict__ Wsel,
    const float* __restrict__ bsel, float* __restrict__ wts)
{
    const int wave = threadIdx.x >> 6;
    const int lane = threadIdx.x & 63;
    const int tok0 = blockIdx.x * 32 + wave * 8;   // 8 tokens per wave

    float a[64];
#pragma unroll
    for (int q = 0; q < 64; ++q) a[q] = 0.0f;

    const float* xbase = x + (size_t)tok0 * H_DIM + lane;

#pragma unroll 2
    for (int r = 0; r < 16; ++r) {
        const int h = r * 64 + lane;
        // W row: 8 floats at 32B lane stride -> 2KB span, fully consumed
        const float4 wa = *(const float4*)(Wsel + (size_t)h * NPAT);
        const float4 wb = *(const float4*)(Wsel + (size_t)h * NPAT + 4);
        float xv[8];
#pragma unroll
        for (int j = 0; j < 8; ++j)        // dword, 256B/wave coalesced
            xv[j] = xbase[(size_t)j * H_DIM + r * 64];
#pragma unroll
        for (int j = 0; j < 8; ++j) {
            a[j * 8 + 0] = fmaf(xv[j], wa.x, a[j * 8 + 0]);
            a[j * 8 + 1] = fmaf(xv[j], wa.y, a[j * 8 + 1]);
            a[j * 8 + 2] = fmaf(xv[j], wa.z, a[j * 8 + 2]);
            a[j * 8 + 3] = fmaf(xv[j], wa.w, a[j * 8 + 3]);
            a[j * 8 + 4] = fmaf(xv[j], wb.x, a[j * 8 + 4]);
            a[j * 8 + 5] = fmaf(xv[j], wb.y, a[j * 8 + 5]);
            a[j * 8 + 6] = fmaf(xv[j], wb.z, a[j * 8 + 6]);
            a[j * 8 + 7] = fmaf(xv[j], wb.w, a[j * 8 + 7]);
        }
    }

    // Exchange-halves butterfly: step s binds bit s of q to lane bit s.
    // In-place shrink 64->1; reads a[2m],a[2m+1] always ahead of write a[m].
#pragma unroll
    for (int s = 0; s < 6; ++s) {
        const int o = 1 << s;
        const int half = 32 >> s;
        const bool hib = (lane & o) != 0;
#pragma unroll
        for (int m = 0; m < half; ++m) {
            const float lo = a[2 * m];
            const float hi = a[2 * m + 1];
            const float disc = hib ? lo : hi;
            const float keep = hib ? hi : lo;
            a[m] = keep + __shfl_xor(disc, o, 64);
        }
    }
    // a[0] = logit for token tok0 + (lane>>3), pattern lane&7

    const float logit = a[0] + bsel[lane & 7];     // TEMPERATURE == 1.0

    // softmax across the 8 lanes sharing a token (xor 1,2,4)
    float mx = logit;
    mx = fmaxf(mx, __shfl_xor(mx, 1, 64));
    mx = fmaxf(mx, __shfl_xor(mx, 2, 64));
    mx = fmaxf(mx, __shfl_xor(mx, 4, 64));
    const float e = __expf(logit - mx);
    float sum = e;
    sum += __shfl_xor(sum, 1, 64);
    sum += __shfl_xor(sum, 2, 64);
    sum += __shfl_xor(sum, 4, 64);

    // lane l -> wts[(tok0 + l>>3)*8 + (l&7)] = wts[tok0*8 + l]: coalesced
    wts[(size_t)tok0 * NPAT + lane] = e / sum;
}

// ---------------- Kernel B: fused variation + EMA + add ------------------
// Block = (b, chunk, h-slice). 256 threads, thread tid owns ONE column
// h = hs*256 + tid across the chunk's tokens. 2048 blocks -> 32 waves/CU.
__global__ __launch_bounds__(256) void kB_fused(
    const float* __restrict__ x, const float* __restrict__ noise,
    const float* __restrict__ patterns, const float* __restrict__ wts,
    float* __restrict__ out)
{
    __shared__ float wsm[CHUNK * NPAT];   // 2 KB: this chunk's token weights

    const int cid = blockIdx.x;                 // 0 .. B*NCHUNK*HSPLIT-1
    const int hs  = cid & (HSPLIT - 1);
    const int bc  = cid >> 2;                   // b*NCHUNK + c
    const int b   = bc >> 7;                    // / NCHUNK (=128)
    const int c   = bc & (NCHUNK - 1);
    const int t0  = c * CHUNK;
    const size_t tokbase = (size_t)b * T_LEN + t0;
    const int tid = threadIdx.x;
    const int h   = hs * HSL + tid;             // this thread's column

    // stage weights for CHUNK tokens: 64*8 = 512 floats, 2 per thread
    *(float2*)(wsm + tid * 2) = *(const float2*)(wts + tokbase * NPAT + tid * 2);
    __syncthreads();

    float pat[NPAT];
#pragma unroll
    for (int p = 0; p < NPAT; ++p)
        pat[p] = patterns[p * H_DIM + h];

    // EMA warm-up: 64 truncated-history steps (chunk 0 is exact from t=0).
    // Reads = previous chunk's noise, just streamed by its own block -> LLC.
    float s = 0.0f;
    const int nw = (c == 0) ? 0 : WARM;
    const float* nptr = noise + (tokbase - nw) * (size_t)H_DIM + h;
#pragma unroll 8
    for (int i = 0; i < nw; ++i) {
        s = fmaf(0.9f, s, 0.005f * (*nptr));
        nptr += H_DIM;
    }

    const float* xptr = x + tokbase * H_DIM + h;
    float*       optr = out + tokbase * H_DIM + h;
#pragma unroll 8
    for (int i = 0; i < CHUNK; ++i) {
        const float nv = *nptr;
        const float xv = *xptr;
        s = fmaf(0.9f, s, 0.005f * nv);

        // uniform-address LDS reads (broadcast, conflict-free)
        const float4 wA = *(const float4*)(wsm + i * NPAT);
        const float4 wB = *(const float4*)(wsm + i * NPAT + 4);
        float v = 0.0f;
        v = fmaf(wA.x, pat[0], v);
        v = fmaf(wA.y, pat[1], v);
        v = fmaf(wA.z, pat[2], v);
        v = fmaf(wA.w, pat[3], v);
        v = fmaf(wB.x, pat[4], v);
        v = fmaf(wB.y, pat[5], v);
        v = fmaf(wB.z, pat[6], v);
        v = fmaf(wB.w, pat[7], v);

        *optr = xv + v + s;
        nptr += H_DIM; xptr += H_DIM; optr += H_DIM;
    }
}

extern "C" void kernel_launch(void* const* d_in, const int* in_sizes, int n_in,
                              void* d_out, int out_size, void* d_ws, size_t ws_size,
                              hipStream_t stream) {
    const float* x        = (const float*)d_in[0];  // [B,T,H]
    const float* Wsel     = (const float*)d_in[1];  // [H,8]
    const float* bsel     = (const float*)d_in[2];  // [8]
    const float* patterns = (const float*)d_in[3];  // [8,H]
    const float* noise    = (const float*)d_in[4];  // [B,T,H]
    float* out = (float*)d_out;
    float* wts = (float*)d_ws;                      // [B,T,8] = 1 MB scratch

    const int n_tok = B_DIM * T_LEN;                // 32768
    kA_weights<<<n_tok / 32, 256, 0, stream>>>(x, Wsel, bsel, wts);
    kB_fused<<<B_DIM * NCHUNK * HSPLIT, 256, 0, stream>>>(x, noise, patterns, wts, out);
}

// Round 3
// 358.061 us; speedup vs baseline: 1.0509x; 1.0509x over previous
//
#include <hip/hip_runtime.h>

// NaturalVariation: out = x + softmax(x@W_sel + b_sel)@patterns + EMA(0.05*noise)
// B=4, T=8192, H=1024, P=8. fp32 in/out.
//
// EMA truncation: 0.9^64 = 1.18e-3 -> worst-case dropped tail ~3e-4 << tol.
// Chunks of 128 tokens are independent given a 64-step warm-up.
//
// R3: FUSED single kernel. Accounting across R0-R2 shows total-kB is a
// constant ~258us while kA was rewritten twice => kA ~90us + ~165us fixed
// harness residual. kA's x pass (128MB) is fully redundant with kB's.
// Fusion: block = (b, chunk) x full H, 1024 threads, thread owns column
// h=tid. Per 8-token subtile: x -> regs (read ONCE), per-wave 64-product
// exchange-halves butterfly (R2-verified) reduces the wave's 64-col stripe,
// padded-LDS cross-wave sum, redundant softmax (R2-verified 8-lane-group),
// __shfl weight broadcast, then EMA+variation+store. EMA state lives in a
// register across the whole chunk. Traffic: 128+192+128 = 448MB ~ 71us floor.

#define T_LEN 8192
#define H_DIM 1024
#define B_DIM 4
#define NPAT 8
#define CHUNK 128            // tokens per block
#define SUB 8                // tokens per butterfly subtile
#define NSUB (CHUNK / SUB)   // 16
#define WARM 64              // EMA warm-up steps
#define NCHUNK (T_LEN / CHUNK)   // 64 chunks per batch row
#define RSTR 17              // LDS reduce stride (pad: 17 -> 2 lanes/bank max)

static_assert(WARM <= CHUNK, "warm-up must stay within previous chunk");

// ---------------- Fused kernel ------------------------------------------
// grid = B*NCHUNK = 256 blocks of 1024 threads (16 waves; 1 block/CU).
__global__ __launch_bounds__(1024, 4) void kF_fused(
    const float* __restrict__ x, const float* __restrict__ noise,
    const float* __restrict__ Wsel, const float* __restrict__ bsel,
    const float* __restrict__ patterns, float* __restrict__ out)
{
    __shared__ float red[2][64 * RSTR];   // [buf][slot*RSTR + wave], 8.7KB

    const int tid  = threadIdx.x;
    const int wave = tid >> 6;            // 0..15
    const int lane = tid & 63;
    const int b    = blockIdx.x >> 6;     // / NCHUNK
    const int c    = blockIdx.x & (NCHUNK - 1);
    const size_t tokbase = (size_t)b * T_LEN + c * CHUNK;
    const int h    = tid;                 // this thread's column (0..1023)

    // Per-column constants (32KB W table + 32KB patterns: L1/L2 hot)
    const float4 wa = *(const float4*)(Wsel + (size_t)h * NPAT);
    const float4 wb = *(const float4*)(Wsel + (size_t)h * NPAT + 4);
    float pat[NPAT];
#pragma unroll
    for (int p = 0; p < NPAT; ++p) pat[p] = patterns[p * H_DIM + h];
    const float bs = bsel[lane & 7];      // bias of the slot this lane owns

    // EMA warm-up: 64 truncated-history steps (chunk 0 exact from t=0).
    float s = 0.0f;
    const int nw = (c == 0) ? 0 : WARM;
    const float* nptr = noise + (tokbase - nw) * (size_t)H_DIM + h;
#pragma unroll 8
    for (int i = 0; i < nw; ++i) {
        s = fmaf(0.9f, s, 0.005f * (*nptr));
        nptr += H_DIM;
    }
    // nptr now points at noise[tokbase][h]

    const float* xld = x + tokbase * H_DIM + h;   // x prefetch cursor
    float*       optr = out + tokbase * H_DIM + h;

    // prefetch subtile 0's x
    float xc[SUB];
#pragma unroll
    for (int j = 0; j < SUB; ++j)
        xc[j] = xld[(size_t)j * H_DIM];
    xld += (size_t)SUB * H_DIM;

    for (int st = 0; st < NSUB; ++st) {
        const int buf = st & 1;

        // ---- phase 1: stripe-partial logits for 8 tokens ----
        // a[j*8+p] = x[t_j][h] * W[h][p]; butterfly sums over the wave's
        // 64 lanes (= 64 columns of this wave's stripe).
        float a[64];
#pragma unroll
        for (int j = 0; j < SUB; ++j) {
            a[j * 8 + 0] = xc[j] * wa.x;
            a[j * 8 + 1] = xc[j] * wa.y;
            a[j * 8 + 2] = xc[j] * wa.z;
            a[j * 8 + 3] = xc[j] * wa.w;
            a[j * 8 + 4] = xc[j] * wb.x;
            a[j * 8 + 5] = xc[j] * wb.y;
            a[j * 8 + 6] = xc[j] * wb.z;
            a[j * 8 + 7] = xc[j] * wb.w;
        }
        // exchange-halves butterfly (verified in R2 kA): after 6 steps,
        // a[0] at lane l = stripe sum for (token st*8 + (l>>3), pat l&7)
#pragma unroll
        for (int sp = 0; sp < 6; ++sp) {
            const int o = 1 << sp;
            const int half = 32 >> sp;
            const bool hib = (lane & o) != 0;
#pragma unroll
            for (int m = 0; m < half; ++m) {
                const float lo = a[2 * m];
                const float hi = a[2 * m + 1];
                const float disc = hib ? lo : hi;
                const float keep = hib ? hi : lo;
                a[m] = keep + __shfl_xor(disc, o, 64);
            }
        }
        red[buf][lane * RSTR + wave] = a[0];

        // prefetch next subtile's x BEFORE the barrier (hides HBM latency)
        float xn[SUB];
        if (st + 1 < NSUB) {
#pragma unroll
            for (int j = 0; j < SUB; ++j)
                xn[j] = xld[(size_t)j * H_DIM];
            xld += (size_t)SUB * H_DIM;
        }

        __syncthreads();

        // ---- cross-wave sum (redundant on all lanes) + softmax ----
        float tot = 0.0f;
#pragma unroll
        for (int w = 0; w < 16; ++w)
            tot += red[buf][lane * RSTR + w];
        const float logit = tot + bs;     // TEMPERATURE == 1.0

        // softmax across the 8 lanes sharing a token (verified pattern)
        float mx = logit;
        mx = fmaxf(mx, __shfl_xor(mx, 1, 64));
        mx = fmaxf(mx, __shfl_xor(mx, 2, 64));
        mx = fmaxf(mx, __shfl_xor(mx, 4, 64));
        const float e = __expf(logit - mx);
        float den = e;
        den += __shfl_xor(den, 1, 64);
        den += __shfl_xor(den, 2, 64);
        den += __shfl_xor(den, 4, 64);
        const float wgt = e / den;        // weight of (token l>>3, pat l&7)

        // ---- phase 2: EMA + variation + store for the 8 tokens ----
#pragma unroll
        for (int j = 0; j < SUB; ++j) {
            const float w0 = __shfl(wgt, j * 8 + 0, 64);
            const float w1 = __shfl(wgt, j * 8 + 1, 64);
            const float w2 = __shfl(wgt, j * 8 + 2, 64);
            const float w3 = __shfl(wgt, j * 8 + 3, 64);
            const float w4 = __shfl(wgt, j * 8 + 4, 64);
            const float w5 = __shfl(wgt, j * 8 + 5, 64);
            const float w6 = __shfl(wgt, j * 8 + 6, 64);
            const float w7 = __shfl(wgt, j * 8 + 7, 64);

            const float nv = *nptr;
            s = fmaf(0.9f, s, 0.005f * nv);

            float v = 0.0f;
            v = fmaf(w0, pat[0], v);
            v = fmaf(w1, pat[1], v);
            v = fmaf(w2, pat[2], v);
            v = fmaf(w3, pat[3], v);
            v = fmaf(w4, pat[4], v);
            v = fmaf(w5, pat[5], v);
            v = fmaf(w6, pat[6], v);
            v = fmaf(w7, pat[7], v);

            *optr = xc[j] + v + s;
            nptr += H_DIM;
            optr += H_DIM;
        }

        // rotate prefetch buffer
#pragma unroll
        for (int j = 0; j < SUB; ++j) xc[j] = xn[j];
    }
}

extern "C" void kernel_launch(void* const* d_in, const int* in_sizes, int n_in,
                              void* d_out, int out_size, void* d_ws, size_t ws_size,
                              hipStream_t stream) {
    const float* x        = (const float*)d_in[0];  // [B,T,H]
    const float* Wsel     = (const float*)d_in[1];  // [H,8]
    const float* bsel     = (const float*)d_in[2];  // [8]
    const float* patterns = (const float*)d_in[3];  // [8,H]
    const float* noise    = (const float*)d_in[4];  // [B,T,H]
    float* out = (float*)d_out;
    (void)d_ws; (void)ws_size;

    kF_fused<<<B_DIM * NCHUNK, 1024, 0, stream>>>(x, noise, Wsel, bsel,
                                                  patterns, out);
}